// Round 3
// baseline (215.798 us; speedup 1.0000x reference)
//
#include <hip/hip_runtime.h>
#include <hip/hip_bf16.h>

// InstanceAttentionModule: B=32, H=W=32 (HW=1024), C=256, F=64, K_NEIGH=32.
// Round-11 (structural): U (64MB) / E / Z intermediates ELIMINATED.
//   k_R    : gram -> e -> rowsum R only (pass-1 of old k_scores, no E_lds,
//            no pass 2, no U write). Tiny LDS -> full occupancy.
//   k_out2 : flash-style fusion. Per block (64 rows x 256 cols x 1 batch),
//            sweep j in steps of 32: stage emb-j tile (swizzled-src
//            global_load_lds, conflict-free) + scT tile (unit-transposed
//            [quad][c] layout, conflict-free) -> gram MFMA (swapped operands,
//            lane owns 4 consecutive j of its own q-row) -> e -> u in regs
//            (bit-exact same chain as k_R) -> cvt_pk -> P_lds -> PV MFMA.
//            z accumulated in-register (block sees all j); out = x + acc/z.
//   k_prep, k_lin unchanged.

typedef short bf16x8 __attribute__((ext_vector_type(8)));
typedef float f32x4 __attribute__((ext_vector_type(4)));

#define LOG2E 1.4426950408889634f

__device__ __forceinline__ unsigned short f2bf(float f) {
  unsigned u = __float_as_uint(f);
  u += 0x7fffu + ((u >> 16) & 1u);   // round-to-nearest-even
  return (unsigned short)(u >> 16);
}
__device__ __forceinline__ float bf2f(unsigned short h) {
  return __uint_as_float(((unsigned)h) << 16);
}
__device__ __forceinline__ unsigned pack2(float a, float b) {
  return (unsigned)f2bf(a) | ((unsigned)f2bf(b) << 16);
}
__device__ __forceinline__ unsigned cvtpk(float lo, float hi) {
  unsigned r;
  asm("v_cvt_pk_bf16_f32 %0, %1, %2" : "=v"(r) : "v"(lo), "v"(hi));
  return r;
}
__device__ __forceinline__ float exp2x(float x) {   // 2^x, single v_exp_f32
  float r;
  asm("v_exp_f32 %0, %1" : "=v"(r) : "v"(x));
  return r;
}
__device__ __forceinline__ f32x4 mfma16(bf16x8 a, bf16x8 b, f32x4 c) {
  return __builtin_amdgcn_mfma_f32_16x16x32_bf16(a, b, c, 0, 0, 0);
}
__device__ __forceinline__ int iabs(int v) { return v < 0 ? -v : v; }
__device__ __forceinline__ void load_lds16(const void* g, void* l) {
  __builtin_amdgcn_global_load_lds(
      (const __attribute__((address_space(1))) unsigned int*)g,
      (__attribute__((address_space(3))) unsigned int*)l, 16, 0, 0);
}

// the shared e-chain: MUST be bit-identical in k_R and k_out2
__device__ __forceinline__ float e_chain(float g, float nsq2i, float sq2j,
                                         int diff) {
  float w2 = fminf(fmaf(2.f * LOG2E, g, nsq2i - sq2j), 0.f);
  float fd = (float)diff;
  float fs = (diff <= 32) ? fd : 0.f;
  return exp2x(fmaf(exp2x(w2), LOG2E, fmaf(fs, LOG2E / 32.f, -LOG2E)));
}

// ---------------------------------------------------------------- k_prep
// grid 80 x 256, 4 elems/thread: Wb = bf16(embW rows 0..63 || attnW rows 64..319)
__global__ __launch_bounds__(256) void k_prep(const float* __restrict__ embW,
                                              const float* __restrict__ attnW,
                                              unsigned short* __restrict__ Wb) {
  const int i = (blockIdx.x * 256 + threadIdx.x) * 4;   // 0..81916
  float4 v = (i < 16384) ? *(const float4*)(embW + i)
                         : *(const float4*)(attnW + (i - 16384));
  ushort4 p; p.x = f2bf(v.x); p.y = f2bf(v.y); p.z = f2bf(v.z); p.w = f2bf(v.w);
  *(ushort4*)(Wb + i) = p;
}

// ---------------------------------------------------------------- k_lin
// Fused emb+shortcut. grid 512 (64-row M-tiles), block 256 = 4 waves (2x2).
// sq2 and T2 outputs are PRE-SCALED by log2(e) for the exp2 domain.
__global__ __launch_bounds__(256) void k_lin(const float* __restrict__ x,
                                             const unsigned short* __restrict__ Wb,
                                             const float* __restrict__ embB,
                                             const float* __restrict__ attnB,
                                             const float* __restrict__ thrW,
                                             const float* __restrict__ thrB,
                                             unsigned short* __restrict__ embb,
                                             float* __restrict__ sq2,
                                             unsigned short* __restrict__ scT,
                                             float* __restrict__ T2out) {
  __shared__ union {
    struct { unsigned short xs[64][40]; unsigned short ws[320][40]; } a;
    unsigned short St[256][72];
  } sm;
  const int t = threadIdx.x;
  const int Mbase = blockIdx.x * 64;
  const int lane = t & 63, wave = t >> 6;
  const int wm = wave >> 1, wn = wave & 1;
  const int l15 = lane & 15, quad = lane >> 4;

  f32x4 acc[2][10] = {};
  for (int k0 = 0; k0 < 256; k0 += 32) {
    { // stage x tile (64x32) from fp32, convert inline
      int row = t >> 2, c0 = (t & 3) * 8;
      const float* src = x + (size_t)(Mbase + row) * 256 + k0 + c0;
      float4 a = *(const float4*)src;
      float4 b = *(const float4*)(src + 4);
      uint4 p; p.x = pack2(a.x, a.y); p.y = pack2(a.z, a.w);
      p.z = pack2(b.x, b.y); p.w = pack2(b.z, b.w);
      *(uint4*)&sm.a.xs[row][c0] = p;
    }
    { // stage weight tile (320x32): pure copies from pre-converted Wb
      const unsigned short* wsrc = Wb + (size_t)t * 256 + k0;
      for (int s = 0; s < 4; s++)
        *(uint4*)&sm.a.ws[t][s * 8] = *(const uint4*)(wsrc + s * 8);
      if (t < 64) {
        const unsigned short* wsrc2 = Wb + (size_t)(256 + t) * 256 + k0;
        for (int s = 0; s < 4; s++)
          *(uint4*)&sm.a.ws[256 + t][s * 8] = *(const uint4*)(wsrc2 + s * 8);
      }
    }
    __syncthreads();
    bf16x8 af[2];
    af[0] = *(const bf16x8*)&sm.a.xs[wm * 32 + l15][quad * 8];
    af[1] = *(const bf16x8*)&sm.a.xs[wm * 32 + 16 + l15][quad * 8];
    for (int nt = 0; nt < 10; nt++) {
      bf16x8 bfr = *(const bf16x8*)&sm.a.ws[wn * 160 + nt * 16 + l15][quad * 8];
      acc[0][nt] = mfma16(af[0], bfr, acc[0][nt]);
      acc[1][nt] = mfma16(af[1], bfr, acc[1][nt]);
    }
    __syncthreads();
  }

  // emb epilogue: wn==0 waves own n<64 (nt 0..3); sq2 from ROUNDED emb.
  if (wn == 0) {
    float sp[2][4] = {{0.f,0.f,0.f,0.f},{0.f,0.f,0.f,0.f}};
    for (int rt = 0; rt < 2; rt++)
      for (int nt = 0; nt < 4; nt++) {
        int n = nt * 16 + l15;
        float bias = embB[n];
        for (int r = 0; r < 4; r++) {
          float v = acc[rt][nt][r] + bias;
          unsigned short hb = f2bf(v);
          int row = wm * 32 + rt * 16 + quad * 4 + r;
          embb[(size_t)(Mbase + row) * 64 + n] = hb;
          float vf = bf2f(hb);
          sp[rt][r] += vf * vf;
        }
      }
    for (int m = 8; m >= 1; m >>= 1)
      for (int rt = 0; rt < 2; rt++)
        for (int r = 0; r < 4; r++)
          sp[rt][r] += __shfl_xor(sp[rt][r], m);
    if (l15 == 0)
      for (int rt = 0; rt < 2; rt++)
        for (int r = 0; r < 4; r++)
          sq2[Mbase + wm * 32 + rt * 16 + quad * 4 + r] = sp[rt][r] * LOG2E;
  }

  // shortcut epilogue -> St transpose buffer
  for (int rt = 0; rt < 2; rt++)
    for (int nt = 0; nt < 10; nt++) {
      int n = wn * 160 + nt * 16 + l15;
      if (n < 64) continue;
      int c = n - 64;
      float bias = attnB[c];
      for (int r = 0; r < 4; r++) {
        float v = acc[rt][nt][r] + bias;
        sm.St[c][wm * 32 + rt * 16 + quad * 4 + r] = f2bf(v);
      }
    }
  __syncthreads();

  const int b = Mbase >> 10, jbase = Mbase & 1023;
  { // coalesced write of scT[b][c][jbase..jbase+64)
    unsigned short* dst = scT + ((size_t)b * 256 + t) * 1024 + jbase;
    for (int s = 0; s < 8; s++)
      *(uint4*)(dst + s * 8) = *(const uint4*)&sm.St[t][s * 8];
  }
  { // Tinst (pre-scaled by log2e)
    float tp = 0.f;
    int j = t >> 2, cs = (t & 3) * 64;
    for (int c = 0; c < 64; c++)
      tp += bf2f(sm.St[cs + c][j]) * thrW[cs + c];
    tp += __shfl_xor(tp, 1);
    tp += __shfl_xor(tp, 2);
    if ((t & 3) == 0) T2out[Mbase + j] = (tp + thrB[0]) * LOG2E;
  }
}

// ---------------------------------------------------------------- k_R
// grid 2048 (32 b x 64 strips of 16 rows), block 512 = 8 waves.
// Wave w owns j-eighth [w*128,(w+1)*128): gram MFMA (swapped) -> e -> rowsum.
// Writes only R[b][i]. No E materialization.
__global__ __launch_bounds__(512) void k_R(const unsigned short* __restrict__ embb,
                                           const float* __restrict__ sq2,
                                           float* __restrict__ R) {
  __shared__ float rbuf[16];
  const int t = threadIdx.x, lane = t & 63, wave = t >> 6;
  const int b = blockIdx.x >> 6, rb = (blockIdx.x & 63) * 16;
  const int l15 = lane & 15, quad = lane >> 4;
  const unsigned short* eb = embb + (size_t)b * 1024 * 64;
  const float* sq2b = sq2 + b * 1024;

  if (t < 16) rbuf[t] = 0.f;
  __syncthreads();

  const int i = rb + l15;
  bf16x8 if0 = *(const bf16x8*)(eb + (size_t)i * 64 + quad * 8);
  bf16x8 if1 = *(const bf16x8*)(eb + (size_t)i * 64 + 32 + quad * 8);
  const float nsq2i = -sq2b[i];
  const int yi = i >> 5, xi = i & 31;
  const int jq = wave * 128;
  float rp = 0.f;
  for (int j0 = jq; j0 < jq + 128; j0 += 16) {
    const int jr = j0 + l15;
    bf16x8 jf0 = *(const bf16x8*)(eb + (size_t)jr * 64 + quad * 8);
    bf16x8 jf1 = *(const bf16x8*)(eb + (size_t)jr * 64 + 32 + quad * 8);
    f32x4 g = {0.f, 0.f, 0.f, 0.f};
    g = mfma16(jf0, if0, g);            // D[j][i]: lane row j=quad*4+r, col i=l15
    g = mfma16(jf1, if1, g);
    const int jg = j0 + quad * 4;
    const float4 s4 = *(const float4*)(sq2b + jg);
    const int dy = iabs(yi - (jg >> 5));
    const int dxa = xi - (jg & 31);
    float e0 = e_chain(g[0], nsq2i, s4.x, dy + iabs(dxa));
    float e1 = e_chain(g[1], nsq2i, s4.y, dy + iabs(dxa - 1));
    float e2 = e_chain(g[2], nsq2i, s4.z, dy + iabs(dxa - 2));
    float e3 = e_chain(g[3], nsq2i, s4.w, dy + iabs(dxa - 3));
    rp += (e0 + e1) + (e2 + e3);
  }
  rp += __shfl_xor(rp, 16);
  rp += __shfl_xor(rp, 32);
  if (quad == 0) atomicAdd(&rbuf[l15], rp);
  __syncthreads();
  if (t < 16) R[b * 1024 + rb + t] = rbuf[t];
}

// ---------------------------------------------------------------- k_out2
// Fused scores+PV. grid 512 = 32 b x 16 row-tiles(64), block 256 = 4 waves.
// Wave w: gram rows w*16..w*16+15 (swapped MFMA: lane owns q=w*16+l15,
// 4 consecutive j per quad); PV cols w*64..w*64+63 over all 64 rows.
// LDS: Kb[2] 8KB (emb j-tile, swizzled src) + Sb[2] 32KB (scT, unit-transposed
// [quad-chunk][c] so b128 B-frag reads are conflict-free) + Pb 5KB (pad-40).
__global__ __launch_bounds__(256) void k_out2(const unsigned short* __restrict__ embb,
                                              const float* __restrict__ sq2,
                                              const float* __restrict__ T2,
                                              const float* __restrict__ Rv,
                                              const unsigned short* __restrict__ scT,
                                              const float* __restrict__ x,
                                              float* __restrict__ out) {
  __shared__ unsigned short Kb[2][32 * 64];     // [j-row][k], 128B rows, swz src
  __shared__ unsigned short Sb[2][1024 * 8];    // unit-transposed: unit=h*256+c
  __shared__ unsigned short Pb[64 * 40];        // [q-row][j], pad-40
  __shared__ float zbuf[64];
  const int t = threadIdx.x, lane = t & 63, w = t >> 6;
  const int l15 = lane & 15, quad = lane >> 4;
  const int b = blockIdx.x >> 4, rt = blockIdx.x & 15;
  const unsigned short* eb = embb + (size_t)b * 1024 * 64;
  const float* sq2b = sq2 + b * 1024;
  const float* T2b = T2 + b * 1024;

  // per-lane fixed gram state: q-row gi
  const int qrow = w * 16 + l15;                // 0..63 in block
  const int gi = rt * 64 + qrow;                // 0..1023 in batch
  bf16x8 qf0 = *(const bf16x8*)(eb + (size_t)gi * 64 + quad * 8);
  bf16x8 qf1 = *(const bf16x8*)(eb + (size_t)gi * 64 + 32 + quad * 8);
  const float nsq2q = -sq2b[gi];
  const float invR2 = LOG2E / Rv[b * 1024 + gi];
  const int yi = gi >> 5, xi = gi & 31;

  // staging geometry
  // Kb: thread t -> LDS 16B unit t of the 4KB tile; elem (row=t>>3, chunk=t&7);
  //     source chunk pre-swizzled: chunk' = (t&7) ^ (row&7)
  const int krow = t >> 3;
  const int kchunk = (t & 7) ^ (krow & 7);
  // Sb: unit u = h*256 + c (h=j-chunk 0..3, c=scT row). Thread t stages row
  //     c=t's 4 chunks at units k*256+t (wave-uniform base + lane*16 each).
  const unsigned short* srow = scT + ((size_t)b * 256 + t) * 1024;

#define STAGE(bufi, j0s)                                                     \
  do {                                                                       \
    load_lds16(eb + (size_t)((j0s) + krow) * 64 + kchunk * 8,                \
               &Kb[bufi][t * 8]);                                            \
    load_lds16(srow + (j0s), &Sb[bufi][(0 * 256 + t) * 8]);                  \
    load_lds16(srow + (j0s) + 8, &Sb[bufi][(1 * 256 + t) * 8]);              \
    load_lds16(srow + (j0s) + 16, &Sb[bufi][(2 * 256 + t) * 8]);             \
    load_lds16(srow + (j0s) + 24, &Sb[bufi][(3 * 256 + t) * 8]);             \
  } while (0)

  STAGE(0, 0);
  __syncthreads();                               // drains vmcnt: buf0 ready

  f32x4 acc[4][4] = {};
  float zloc = 0.f;
  const int sw = l15 & 7;                        // Kb read swizzle key

  for (int it = 0; it < 32; ++it) {
    const int cur = it & 1;
    const int j0 = it * 32;
    if (it < 31) STAGE(cur ^ 1, j0 + 32);        // prefetch next j-step

    // ---- gram: P[j][q] for j in [j0, j0+32), q = w*16+l15
    bf16x8 kf00 = *(const bf16x8*)&Kb[cur][(l15) * 64 + ((0 * 4 + quad) ^ sw) * 8];
    bf16x8 kf01 = *(const bf16x8*)&Kb[cur][(l15) * 64 + ((1 * 4 + quad) ^ sw) * 8];
    bf16x8 kf10 = *(const bf16x8*)&Kb[cur][(16 + l15) * 64 + ((0 * 4 + quad) ^ sw) * 8];
    bf16x8 kf11 = *(const bf16x8*)&Kb[cur][(16 + l15) * 64 + ((1 * 4 + quad) ^ sw) * 8];
    f32x4 g0 = {0.f, 0.f, 0.f, 0.f}, g1 = {0.f, 0.f, 0.f, 0.f};
    g0 = mfma16(kf00, qf0, g0);                  // same k-half order as k_R
    g0 = mfma16(kf01, qf1, g0);
    g1 = mfma16(kf10, qf0, g1);
    g1 = mfma16(kf11, qf1, g1);

    // ---- e -> u transform (bit-exact e_chain vs k_R), pack, stage to Pb
    #pragma unroll
    for (int jt = 0; jt < 2; ++jt) {
      const f32x4 g = jt ? g1 : g0;
      const int jg = j0 + jt * 16 + quad * 4;
      const float4 s4 = *(const float4*)(sq2b + jg);
      const float4 t4 = *(const float4*)(T2b + jg);
      const int dy = iabs(yi - (jg >> 5));
      const int dxa = xi - (jg & 31);
      float e0 = e_chain(g[0], nsq2q, s4.x, dy + iabs(dxa));
      float e1 = e_chain(g[1], nsq2q, s4.y, dy + iabs(dxa - 1));
      float e2 = e_chain(g[2], nsq2q, s4.z, dy + iabs(dxa - 2));
      float e3 = e_chain(g[3], nsq2q, s4.w, dy + iabs(dxa - 3));
      float u0 = exp2x(fmaxf(fmaf(e0, invR2, -t4.x), 0.f));
      float u1 = exp2x(fmaxf(fmaf(e1, invR2, -t4.y), 0.f));
      float u2 = exp2x(fmaxf(fmaf(e2, invR2, -t4.z), 0.f));
      float u3 = exp2x(fmaxf(fmaf(e3, invR2, -t4.w), 0.f));
      unsigned pk0 = cvtpk(u0, u1);
      unsigned pk1 = cvtpk(u2, u3);
      // z sums the ROUNDED u used by the GEMM
      zloc += __uint_as_float(pk0 << 16) + __uint_as_float(pk0 & 0xffff0000u);
      zloc += __uint_as_float(pk1 << 16) + __uint_as_float(pk1 & 0xffff0000u);
      uint2 pk; pk.x = pk0; pk.y = pk1;
      *(uint2*)&Pb[qrow * 40 + jt * 16 + quad * 4] = pk;
    }
    __syncthreads();   // Pb visible; prefetched gloads also drained here

    // ---- PV: acc[i][n] += P(rows i*16+l15) x scT(cols w*64+n*16+l15)
    bf16x8 af[4], bfv[4];
    #pragma unroll
    for (int i = 0; i < 4; i++)
      af[i] = *(const bf16x8*)&Pb[(i * 16 + l15) * 40 + quad * 8];
    #pragma unroll
    for (int n = 0; n < 4; n++)
      bfv[n] = *(const bf16x8*)&Sb[cur][(quad * 256 + w * 64 + n * 16 + l15) * 8];
    #pragma unroll
    for (int i = 0; i < 4; i++)
      #pragma unroll
      for (int n = 0; n < 4; n++)
        acc[i][n] = mfma16(af[i], bfv[n], acc[i][n]);
    __syncthreads();   // protect Pb (rewritten next step)
  }
#undef STAGE

  // ---- z handoff + epilogue
  zloc += __shfl_xor(zloc, 16);
  zloc += __shfl_xor(zloc, 32);
  if (quad == 0) zbuf[qrow] = zloc;
  __syncthreads();

  #pragma unroll
  for (int i = 0; i < 4; i++) {
    const int rowl = i * 16 + quad * 4;
    float iz[4];
    #pragma unroll
    for (int r = 0; r < 4; r++) iz[r] = 1.f / zbuf[rowl + r];
    const int grow = b * 1024 + rt * 64 + rowl;
    #pragma unroll
    for (int n = 0; n < 4; n++) {
      const int c = w * 64 + n * 16 + l15;
      #pragma unroll
      for (int r = 0; r < 4; r++) {
        size_t idx = (size_t)(grow + r) * 256 + c;
        out[idx] = x[idx] + acc[i][n][r] * iz[r];
      }
    }
  }
}

// ---------------------------------------------------------------- launch
extern "C" void kernel_launch(void* const* d_in, const int* in_sizes, int n_in,
                              void* d_out, int out_size, void* d_ws, size_t ws_size,
                              hipStream_t stream) {
  const float* x     = (const float*)d_in[0];
  const float* embW  = (const float*)d_in[1];
  const float* embB  = (const float*)d_in[2];
  const float* attnW = (const float*)d_in[3];
  const float* attnB = (const float*)d_in[4];
  const float* thrW  = (const float*)d_in[5];
  const float* thrB  = (const float*)d_in[6];
  float* out = (float*)d_out;

  char* ws = (char*)d_ws;
  // layout: embb 4MB | scT 16MB | Wb 160KB | sq2/T2/R tail  (U/E/Z gone)
  unsigned short* embb = (unsigned short*)(ws);
  unsigned short* scT  = (unsigned short*)(ws + (4ull << 20));
  unsigned short* Wb   = (unsigned short*)(ws + (20ull << 20));
  float* sq2 = (float*)(ws + (84ull << 20));
  float* T2  = (float*)(ws + (84ull << 20) + (128ull << 10));
  float* Rv  = (float*)(ws + (84ull << 20) + (256ull << 10));

  k_prep<<<80, 256, 0, stream>>>(embW, attnW, Wb);
  k_lin<<<512, 256, 0, stream>>>(x, Wb, embB, attnB, thrW, thrB, embb, sq2, scT, T2);
  k_R<<<2048, 512, 0, stream>>>(embb, sq2, Rv);
  k_out2<<<512, 256, 0, stream>>>(embb, sq2, T2, Rv, scT, x, out);
}

// Round 4
// 197.996 us; speedup vs baseline: 1.0899x; 1.0899x over previous
//
#include <hip/hip_runtime.h>
#include <hip/hip_bf16.h>

// InstanceAttentionModule: B=32, H=W=32 (HW=1024), C=256, F=64, K_NEIGH=32.
// Round-12: 3 kernels (k_prep, k_lin, k_out2). k_R DELETED:
//   k_out2 pass-0 computes R fully in-register (the per-lane gram q-row in
//   pass-2 is exactly the row whose sum R that lane needs -> j-sweep rowsum,
//   shfl-reduce over quads, R never touches memory). Same total gram FLOPs,
//   one fewer kernel launch + no embb re-read + no R round-trip.
//   k_out2 also gets:
//     - batch->XCD locality: b = bid&31, rt = bid>>5 (round-robin dispatch
//       puts all 16 tiles of batch b on XCD b%8; 4 batches/XCD ~2.6MB < L2)
//     - Pb double-buffer -> ONE barrier per pass-2 j-step (was 2)
//   k_prep, k_lin unchanged.

typedef short bf16x8 __attribute__((ext_vector_type(8)));
typedef float f32x4 __attribute__((ext_vector_type(4)));

#define LOG2E 1.4426950408889634f

__device__ __forceinline__ unsigned short f2bf(float f) {
  unsigned u = __float_as_uint(f);
  u += 0x7fffu + ((u >> 16) & 1u);   // round-to-nearest-even
  return (unsigned short)(u >> 16);
}
__device__ __forceinline__ float bf2f(unsigned short h) {
  return __uint_as_float(((unsigned)h) << 16);
}
__device__ __forceinline__ unsigned pack2(float a, float b) {
  return (unsigned)f2bf(a) | ((unsigned)f2bf(b) << 16);
}
__device__ __forceinline__ unsigned cvtpk(float lo, float hi) {
  unsigned r;
  asm("v_cvt_pk_bf16_f32 %0, %1, %2" : "=v"(r) : "v"(lo), "v"(hi));
  return r;
}
__device__ __forceinline__ float exp2x(float x) {   // 2^x, single v_exp_f32
  float r;
  asm("v_exp_f32 %0, %1" : "=v"(r) : "v"(x));
  return r;
}
__device__ __forceinline__ f32x4 mfma16(bf16x8 a, bf16x8 b, f32x4 c) {
  return __builtin_amdgcn_mfma_f32_16x16x32_bf16(a, b, c, 0, 0, 0);
}
__device__ __forceinline__ int iabs(int v) { return v < 0 ? -v : v; }
__device__ __forceinline__ void load_lds16(const void* g, void* l) {
  __builtin_amdgcn_global_load_lds(
      (const __attribute__((address_space(1))) unsigned int*)g,
      (__attribute__((address_space(3))) unsigned int*)l, 16, 0, 0);
}

// the e-chain used by BOTH pass-0 (R) and pass-2 (u) -> bit-identical
__device__ __forceinline__ float e_chain(float g, float nsq2i, float sq2j,
                                         int diff) {
  float w2 = fminf(fmaf(2.f * LOG2E, g, nsq2i - sq2j), 0.f);
  float fd = (float)diff;
  float fs = (diff <= 32) ? fd : 0.f;
  return exp2x(fmaf(exp2x(w2), LOG2E, fmaf(fs, LOG2E / 32.f, -LOG2E)));
}

// ---------------------------------------------------------------- k_prep
// grid 80 x 256, 4 elems/thread: Wb = bf16(embW rows 0..63 || attnW rows 64..319)
__global__ __launch_bounds__(256) void k_prep(const float* __restrict__ embW,
                                              const float* __restrict__ attnW,
                                              unsigned short* __restrict__ Wb) {
  const int i = (blockIdx.x * 256 + threadIdx.x) * 4;   // 0..81916
  float4 v = (i < 16384) ? *(const float4*)(embW + i)
                         : *(const float4*)(attnW + (i - 16384));
  ushort4 p; p.x = f2bf(v.x); p.y = f2bf(v.y); p.z = f2bf(v.z); p.w = f2bf(v.w);
  *(ushort4*)(Wb + i) = p;
}

// ---------------------------------------------------------------- k_lin
// Fused emb+shortcut. grid 512 (64-row M-tiles), block 256 = 4 waves (2x2).
// sq2 and T2 outputs are PRE-SCALED by log2(e) for the exp2 domain.
__global__ __launch_bounds__(256) void k_lin(const float* __restrict__ x,
                                             const unsigned short* __restrict__ Wb,
                                             const float* __restrict__ embB,
                                             const float* __restrict__ attnB,
                                             const float* __restrict__ thrW,
                                             const float* __restrict__ thrB,
                                             unsigned short* __restrict__ embb,
                                             float* __restrict__ sq2,
                                             unsigned short* __restrict__ scT,
                                             float* __restrict__ T2out) {
  __shared__ union {
    struct { unsigned short xs[64][40]; unsigned short ws[320][40]; } a;
    unsigned short St[256][72];
  } sm;
  const int t = threadIdx.x;
  const int Mbase = blockIdx.x * 64;
  const int lane = t & 63, wave = t >> 6;
  const int wm = wave >> 1, wn = wave & 1;
  const int l15 = lane & 15, quad = lane >> 4;

  f32x4 acc[2][10] = {};
  for (int k0 = 0; k0 < 256; k0 += 32) {
    { // stage x tile (64x32) from fp32, convert inline
      int row = t >> 2, c0 = (t & 3) * 8;
      const float* src = x + (size_t)(Mbase + row) * 256 + k0 + c0;
      float4 a = *(const float4*)src;
      float4 b = *(const float4*)(src + 4);
      uint4 p; p.x = pack2(a.x, a.y); p.y = pack2(a.z, a.w);
      p.z = pack2(b.x, b.y); p.w = pack2(b.z, b.w);
      *(uint4*)&sm.a.xs[row][c0] = p;
    }
    { // stage weight tile (320x32): pure copies from pre-converted Wb
      const unsigned short* wsrc = Wb + (size_t)t * 256 + k0;
      for (int s = 0; s < 4; s++)
        *(uint4*)&sm.a.ws[t][s * 8] = *(const uint4*)(wsrc + s * 8);
      if (t < 64) {
        const unsigned short* wsrc2 = Wb + (size_t)(256 + t) * 256 + k0;
        for (int s = 0; s < 4; s++)
          *(uint4*)&sm.a.ws[256 + t][s * 8] = *(const uint4*)(wsrc2 + s * 8);
      }
    }
    __syncthreads();
    bf16x8 af[2];
    af[0] = *(const bf16x8*)&sm.a.xs[wm * 32 + l15][quad * 8];
    af[1] = *(const bf16x8*)&sm.a.xs[wm * 32 + 16 + l15][quad * 8];
    for (int nt = 0; nt < 10; nt++) {
      bf16x8 bfr = *(const bf16x8*)&sm.a.ws[wn * 160 + nt * 16 + l15][quad * 8];
      acc[0][nt] = mfma16(af[0], bfr, acc[0][nt]);
      acc[1][nt] = mfma16(af[1], bfr, acc[1][nt]);
    }
    __syncthreads();
  }

  // emb epilogue: wn==0 waves own n<64 (nt 0..3); sq2 from ROUNDED emb.
  if (wn == 0) {
    float sp[2][4] = {{0.f,0.f,0.f,0.f},{0.f,0.f,0.f,0.f}};
    for (int rt = 0; rt < 2; rt++)
      for (int nt = 0; nt < 4; nt++) {
        int n = nt * 16 + l15;
        float bias = embB[n];
        for (int r = 0; r < 4; r++) {
          float v = acc[rt][nt][r] + bias;
          unsigned short hb = f2bf(v);
          int row = wm * 32 + rt * 16 + quad * 4 + r;
          embb[(size_t)(Mbase + row) * 64 + n] = hb;
          float vf = bf2f(hb);
          sp[rt][r] += vf * vf;
        }
      }
    for (int m = 8; m >= 1; m >>= 1)
      for (int rt = 0; rt < 2; rt++)
        for (int r = 0; r < 4; r++)
          sp[rt][r] += __shfl_xor(sp[rt][r], m);
    if (l15 == 0)
      for (int rt = 0; rt < 2; rt++)
        for (int r = 0; r < 4; r++)
          sq2[Mbase + wm * 32 + rt * 16 + quad * 4 + r] = sp[rt][r] * LOG2E;
  }

  // shortcut epilogue -> St transpose buffer
  for (int rt = 0; rt < 2; rt++)
    for (int nt = 0; nt < 10; nt++) {
      int n = wn * 160 + nt * 16 + l15;
      if (n < 64) continue;
      int c = n - 64;
      float bias = attnB[c];
      for (int r = 0; r < 4; r++) {
        float v = acc[rt][nt][r] + bias;
        sm.St[c][wm * 32 + rt * 16 + quad * 4 + r] = f2bf(v);
      }
    }
  __syncthreads();

  const int b = Mbase >> 10, jbase = Mbase & 1023;
  { // coalesced write of scT[b][c][jbase..jbase+64)
    unsigned short* dst = scT + ((size_t)b * 256 + t) * 1024 + jbase;
    for (int s = 0; s < 8; s++)
      *(uint4*)(dst + s * 8) = *(const uint4*)&sm.St[t][s * 8];
  }
  { // Tinst (pre-scaled by log2e)
    float tp = 0.f;
    int j = t >> 2, cs = (t & 3) * 64;
    for (int c = 0; c < 64; c++)
      tp += bf2f(sm.St[cs + c][j]) * thrW[cs + c];
    tp += __shfl_xor(tp, 1);
    tp += __shfl_xor(tp, 2);
    if ((t & 3) == 0) T2out[Mbase + j] = (tp + thrB[0]) * LOG2E;
  }
}

// ---------------------------------------------------------------- k_out2
// Fused R + scores + PV. grid 512 = 16 row-tiles x 32 b (b = bid&31 for
// batch->XCD locality), block 256 = 4 waves.
// Pass 0: j-sweep, gram (swapped MFMA: lane owns q-row w*16+l15, 4 j per
//         quad) -> e_chain -> rp. shfl over quads -> R in REGISTER.
// Pass 2: j-sweep again: gram -> e (same bits) -> u -> Pb[2] -> PV MFMA.
//         ONE barrier per step (Pb double-buffered).
__global__ __launch_bounds__(256) void k_out2(const unsigned short* __restrict__ embb,
                                              const float* __restrict__ sq2,
                                              const float* __restrict__ T2,
                                              const unsigned short* __restrict__ scT,
                                              const float* __restrict__ x,
                                              float* __restrict__ out) {
  __shared__ unsigned short Kb[2][32 * 64];     // emb j-tile, swizzled src
  __shared__ unsigned short Sb[2][1024 * 8];    // scT, unit-transposed
  __shared__ unsigned short Pb[2][64 * 40];     // P tiles, pad-40, DOUBLE-buf
  __shared__ float zbuf[64];
  const int t = threadIdx.x, lane = t & 63, w = t >> 6;
  const int l15 = lane & 15, quad = lane >> 4;
  const int b = blockIdx.x & 31, rt = blockIdx.x >> 5;   // batch->XCD locality
  const unsigned short* eb = embb + (size_t)b * 1024 * 64;
  const float* sq2b = sq2 + b * 1024;
  const float* T2b = T2 + b * 1024;

  // per-lane fixed gram state: q-row gi
  const int qrow = w * 16 + l15;                // 0..63 in block
  const int gi = rt * 64 + qrow;                // 0..1023 in batch
  bf16x8 qf0 = *(const bf16x8*)(eb + (size_t)gi * 64 + quad * 8);
  bf16x8 qf1 = *(const bf16x8*)(eb + (size_t)gi * 64 + 32 + quad * 8);
  const float nsq2q = -sq2b[gi];
  const int yi = gi >> 5, xi = gi & 31;

  // staging geometry
  // Kb: thread t -> LDS 16B unit t; elem (row=t>>3, chunk=t&7); source chunk
  //     pre-swizzled: chunk' = (t&7) ^ (row&7)  (read undoes it with ^sw)
  const int krow = t >> 3;
  const int kchunk = (t & 7) ^ (krow & 7);
  const int sw = l15 & 7;                       // Kb read swizzle key
  // Sb: unit u = h*256 + c (h=j-chunk 0..3, c=scT row).
  const unsigned short* srow = scT + ((size_t)b * 256 + t) * 1024;

#define STAGE_K(bufi, j0s)                                                   \
  load_lds16(eb + (size_t)((j0s) + krow) * 64 + kchunk * 8, &Kb[bufi][t * 8])
#define STAGE_S(bufi, j0s)                                                   \
  do {                                                                       \
    load_lds16(srow + (j0s), &Sb[bufi][(0 * 256 + t) * 8]);                  \
    load_lds16(srow + (j0s) + 8, &Sb[bufi][(1 * 256 + t) * 8]);              \
    load_lds16(srow + (j0s) + 16, &Sb[bufi][(2 * 256 + t) * 8]);             \
    load_lds16(srow + (j0s) + 24, &Sb[bufi][(3 * 256 + t) * 8]);             \
  } while (0)

  // =================== pass 0: R (in-register) ===================
  STAGE_K(0, 0);
  __syncthreads();
  float rp = 0.f;
  #pragma unroll 2
  for (int it = 0; it < 32; ++it) {
    const int cur = it & 1;
    const int j0 = it * 32;
    if (it < 31) STAGE_K(cur ^ 1, j0 + 32);
    bf16x8 kf00 = *(const bf16x8*)&Kb[cur][(l15) * 64 + ((0 * 4 + quad) ^ sw) * 8];
    bf16x8 kf01 = *(const bf16x8*)&Kb[cur][(l15) * 64 + ((1 * 4 + quad) ^ sw) * 8];
    bf16x8 kf10 = *(const bf16x8*)&Kb[cur][(16 + l15) * 64 + ((0 * 4 + quad) ^ sw) * 8];
    bf16x8 kf11 = *(const bf16x8*)&Kb[cur][(16 + l15) * 64 + ((1 * 4 + quad) ^ sw) * 8];
    f32x4 g0 = {0.f, 0.f, 0.f, 0.f}, g1 = {0.f, 0.f, 0.f, 0.f};
    g0 = mfma16(kf00, qf0, g0);
    g0 = mfma16(kf01, qf1, g0);
    g1 = mfma16(kf10, qf0, g1);
    g1 = mfma16(kf11, qf1, g1);
    #pragma unroll
    for (int jt = 0; jt < 2; ++jt) {
      const f32x4 g = jt ? g1 : g0;
      const int jg = j0 + jt * 16 + quad * 4;
      const float4 s4 = *(const float4*)(sq2b + jg);
      const int dy = iabs(yi - (jg >> 5));
      const int dxa = xi - (jg & 31);
      float e0 = e_chain(g[0], nsq2q, s4.x, dy + iabs(dxa));
      float e1 = e_chain(g[1], nsq2q, s4.y, dy + iabs(dxa - 1));
      float e2 = e_chain(g[2], nsq2q, s4.z, dy + iabs(dxa - 2));
      float e3 = e_chain(g[3], nsq2q, s4.w, dy + iabs(dxa - 3));
      rp += (e0 + e1) + (e2 + e3);
    }
    if (it < 31) __syncthreads();
  }
  rp += __shfl_xor(rp, 16);
  rp += __shfl_xor(rp, 32);
  const float invR2 = LOG2E / rp;               // R stays in a register

  // =================== pass 2: scores + PV ===================
  // Kb[0] free (last pass-0 read was Kb[1], all waves past barrier(30));
  // Sb untouched so far.
  STAGE_K(0, 0);
  STAGE_S(0, 0);
  __syncthreads();                               // drains vmcnt: buf0 ready

  f32x4 acc[4][4] = {};
  float zloc = 0.f;
  #pragma unroll 2
  for (int it = 0; it < 32; ++it) {
    const int cur = it & 1;
    const int j0 = it * 32;
    if (it < 31) { STAGE_K(cur ^ 1, j0 + 32); STAGE_S(cur ^ 1, j0 + 32); }

    // ---- gram (identical instruction sequence to pass 0 -> same bits)
    bf16x8 kf00 = *(const bf16x8*)&Kb[cur][(l15) * 64 + ((0 * 4 + quad) ^ sw) * 8];
    bf16x8 kf01 = *(const bf16x8*)&Kb[cur][(l15) * 64 + ((1 * 4 + quad) ^ sw) * 8];
    bf16x8 kf10 = *(const bf16x8*)&Kb[cur][(16 + l15) * 64 + ((0 * 4 + quad) ^ sw) * 8];
    bf16x8 kf11 = *(const bf16x8*)&Kb[cur][(16 + l15) * 64 + ((1 * 4 + quad) ^ sw) * 8];
    f32x4 g0 = {0.f, 0.f, 0.f, 0.f}, g1 = {0.f, 0.f, 0.f, 0.f};
    g0 = mfma16(kf00, qf0, g0);
    g0 = mfma16(kf01, qf1, g0);
    g1 = mfma16(kf10, qf0, g1);
    g1 = mfma16(kf11, qf1, g1);

    // ---- e -> u, pack, stage to Pb[cur]
    #pragma unroll
    for (int jt = 0; jt < 2; ++jt) {
      const f32x4 g = jt ? g1 : g0;
      const int jg = j0 + jt * 16 + quad * 4;
      const float4 s4 = *(const float4*)(sq2b + jg);
      const float4 t4 = *(const float4*)(T2b + jg);
      const int dy = iabs(yi - (jg >> 5));
      const int dxa = xi - (jg & 31);
      float e0 = e_chain(g[0], nsq2q, s4.x, dy + iabs(dxa));
      float e1 = e_chain(g[1], nsq2q, s4.y, dy + iabs(dxa - 1));
      float e2 = e_chain(g[2], nsq2q, s4.z, dy + iabs(dxa - 2));
      float e3 = e_chain(g[3], nsq2q, s4.w, dy + iabs(dxa - 3));
      float u0 = exp2x(fmaxf(fmaf(e0, invR2, -t4.x), 0.f));
      float u1 = exp2x(fmaxf(fmaf(e1, invR2, -t4.y), 0.f));
      float u2 = exp2x(fmaxf(fmaf(e2, invR2, -t4.z), 0.f));
      float u3 = exp2x(fmaxf(fmaf(e3, invR2, -t4.w), 0.f));
      unsigned pk0 = cvtpk(u0, u1);
      unsigned pk1 = cvtpk(u2, u3);
      // z sums the ROUNDED u used by the GEMM
      zloc += __uint_as_float(pk0 << 16) + __uint_as_float(pk0 & 0xffff0000u);
      zloc += __uint_as_float(pk1 << 16) + __uint_as_float(pk1 & 0xffff0000u);
      uint2 pk; pk.x = pk0; pk.y = pk1;
      *(uint2*)&Pb[cur][qrow * 40 + jt * 16 + quad * 4] = pk;
    }
    __syncthreads();   // Pb[cur] visible; prefetched gloads drained;
                       // separates PV(it-1) from Pb[cur^1] rewrite at it+1

    // ---- PV: acc[i][n] += P(rows i*16+l15) x scT(cols w*64+n*16+l15)
    bf16x8 af[4], bfv[4];
    #pragma unroll
    for (int i = 0; i < 4; i++)
      af[i] = *(const bf16x8*)&Pb[cur][(i * 16 + l15) * 40 + quad * 8];
    #pragma unroll
    for (int n = 0; n < 4; n++)
      bfv[n] = *(const bf16x8*)&Sb[cur][(quad * 256 + w * 64 + n * 16 + l15) * 8];
    #pragma unroll
    for (int i = 0; i < 4; i++)
      #pragma unroll
      for (int n = 0; n < 4; n++)
        acc[i][n] = mfma16(af[i], bfv[n], acc[i][n]);
  }
#undef STAGE_K
#undef STAGE_S

  // ---- z handoff + epilogue
  zloc += __shfl_xor(zloc, 16);
  zloc += __shfl_xor(zloc, 32);
  if (quad == 0) zbuf[qrow] = zloc;
  __syncthreads();

  #pragma unroll
  for (int i = 0; i < 4; i++) {
    const int rowl = i * 16 + quad * 4;
    float iz[4];
    #pragma unroll
    for (int r = 0; r < 4; r++) iz[r] = 1.f / zbuf[rowl + r];
    const int grow = b * 1024 + rt * 64 + rowl;
    #pragma unroll
    for (int n = 0; n < 4; n++) {
      const int c = w * 64 + n * 16 + l15;
      #pragma unroll
      for (int r = 0; r < 4; r++) {
        size_t idx = (size_t)(grow + r) * 256 + c;
        out[idx] = x[idx] + acc[i][n][r] * iz[r];
      }
    }
  }
}

// ---------------------------------------------------------------- launch
extern "C" void kernel_launch(void* const* d_in, const int* in_sizes, int n_in,
                              void* d_out, int out_size, void* d_ws, size_t ws_size,
                              hipStream_t stream) {
  const float* x     = (const float*)d_in[0];
  const float* embW  = (const float*)d_in[1];
  const float* embB  = (const float*)d_in[2];
  const float* attnW = (const float*)d_in[3];
  const float* attnB = (const float*)d_in[4];
  const float* thrW  = (const float*)d_in[5];
  const float* thrB  = (const float*)d_in[6];
  float* out = (float*)d_out;

  char* ws = (char*)d_ws;
  // layout: embb 4MB | scT 16MB | Wb 160KB | sq2/T2 tail  (U/E/Z/R gone)
  unsigned short* embb = (unsigned short*)(ws);
  unsigned short* scT  = (unsigned short*)(ws + (4ull << 20));
  unsigned short* Wb   = (unsigned short*)(ws + (20ull << 20));
  float* sq2 = (float*)(ws + (84ull << 20));
  float* T2  = (float*)(ws + (84ull << 20) + (128ull << 10));

  k_prep<<<80, 256, 0, stream>>>(embW, attnW, Wb);
  k_lin<<<512, 256, 0, stream>>>(x, Wb, embB, attnB, thrW, thrB, embb, sq2, scT, T2);
  k_out2<<<512, 256, 0, stream>>>(embb, sq2, T2, scT, x, out);
}